// Round 3
// baseline (5785.506 us; speedup 1.0000x reference)
//
#include <hip/hip_runtime.h>

// GridRNN B=4, S=T=128, H=256, D=3 — MFMA + cross-depth pipelined version.
// 192 wgs in ONE launch: wg (d, bid) handles depth d of chain-group bid.
// Depth d+1 chain r step s consumes depth d chain r step s (X-diagonals and
// Y-rows align across depths) -> depths run concurrently, 1 step skewed,
// handing off through d_out (fp32, in place) guarded by per-(d,group) flags.

#define SS 128
#define TT 128
#define HH 256

typedef _Float16 half8 __attribute__((ext_vector_type(8)));
typedef float float4v __attribute__((ext_vector_type(4)));

__device__ __forceinline__ float fast_tanh(float x) {
    float e = __expf(2.0f * x);
    return 1.0f - 2.0f / (e + 1.0f);
}

__device__ __forceinline__ unsigned short f2hbits(float x) {
    _Float16 h = (_Float16)x;
    return __builtin_bit_cast(unsigned short, h);
}

extern "C" __global__ void __launch_bounds__(512, 2)
grid_rnn_pipe(const float* __restrict__ src, const float* __restrict__ trg,
              const float* __restrict__ Wx_ih, const float* __restrict__ Wx_hh,
              const float* __restrict__ bx_ih, const float* __restrict__ bx_hh,
              const float* __restrict__ Wy_ih, const float* __restrict__ Wy_hh,
              const float* __restrict__ by_ih, const float* __restrict__ by_hh,
              float* __restrict__ out, int* __restrict__ flags)
{
    __shared__ half8 aX[2][512];   // x-input A-frags, double buffered
    __shared__ half8 aH[512];      // h-state A-frags

    const int tid  = threadIdx.x;
    const int lane = tid & 63;
    const int wv   = tid >> 6;     // wave 0..7 -> N-slice n0 = 32*wv
    const int quad = lane >> 4;
    const int l15  = lane & 15;

    const int d    = blockIdx.x >> 6;   // depth 0..2
    const int bid  = blockIdx.x & 63;   // 0..63 (dir+group)
    const int isY  = bid >= 32;
    const int g    = isY ? bid - 32 : bid;
    const int b    = g >> 3;            // batch
    const int c0   = (g & 7) << 4;      // first chain of the 16-chain group
    const int slot = isY;

    const float* Wih = (isY ? Wy_ih : Wx_ih) + (size_t)d * HH * HH;
    const float* Whh = (isY ? Wy_hh : Wx_hh) + (size_t)d * HH * HH;
    const float* bih = (isY ? by_ih : bx_ih) + d * HH;
    const float* bhh = (isY ? by_hh : bx_hh) + d * HH;

    int* myflag   = flags + d * 64 + bid;        // publish (d<2)
    int* prevflag = flags + (d - 1) * 64 + bid;  // poll (d>0)

    const int n0  = wv << 5;
    const int n_0 = n0 + l15;
    const int n_1 = n_0 + 16;

    // ---- B fragments (weights), VGPR/AGPR-resident.
    half8 Bih0[8], Bih1[8], Bhh0[8], Bhh1[8];
    {
        const float* r0i = Wih + (size_t)n_0 * HH;
        const float* r1i = Wih + (size_t)n_1 * HH;
        const float* r0h = Whh + (size_t)n_0 * HH;
        const float* r1h = Whh + (size_t)n_1 * HH;
        auto ldfrag = [&](const float* rowp, int k) -> half8 {
            const float4v u0 = *(const float4v*)(rowp + k);
            const float4v u1 = *(const float4v*)(rowp + k + 4);
            half8 v;
#pragma unroll
            for (int t = 0; t < 4; ++t) { v[t] = (_Float16)u0[t]; v[4 + t] = (_Float16)u1[t]; }
            return v;
        };
#pragma unroll
        for (int f = 0; f < 8; ++f) {
            const int k = (f << 5) + (quad << 3);
            Bih0[f] = ldfrag(r0i, k);
            Bih1[f] = ldfrag(r1i, k);
            Bhh0[f] = ldfrag(r0h, k);
            Bhh1[f] = ldfrag(r1h, k);
        }
    }
    const float bias0 = bih[n_0] + bhh[n_0];
    const float bias1 = bih[n_1] + bhh[n_1];

    // ---- staging: thread tid owns A-frag cell tid: row m=tid&15, k0=(tid>>4)*8.
    const int cm  = tid & 15;
    const int ck0 = (tid >> 4) << 3;
    const int chc = c0 + cm;

    auto stage = [&](int sn) -> half8 {
        const int i = isY ? chc : sn;
        const int j = isY ? sn : ((chc + sn) & 127);
        const size_t cell = (size_t)(b * SS + i) * TT + j;
        const float* row = (d == 0)
            ? (isY ? (trg + (size_t)(b * TT + j) * HH) : (src + (size_t)(b * SS + i) * HH)) + ck0
            : (out + cell * 2 * HH + (size_t)slot * HH + ck0);
        const float4v u0 = *(const float4v*)(row);
        const float4v u1 = *(const float4v*)(row + 4);
        half8 v;
#pragma unroll
        for (int t = 0; t < 4; ++t) { v[t] = (_Float16)u0[t]; v[4 + t] = (_Float16)u1[t]; }
        return v;
    };

    auto waitflag = [&](int target) {
        while (__hip_atomic_load(prevflag, __ATOMIC_ACQUIRE, __HIP_MEMORY_SCOPE_AGENT) < target) {
            __builtin_amdgcn_s_sleep(2);
        }
    };

    // ---- init: stage step 0 (wait for producer's step 0 if d>0), zero h-state.
    if (d > 0) waitflag(1);
    aX[0][tid] = stage(0);
    {
        half8 z;
#pragma unroll
        for (int t = 0; t < 8; ++t) z[t] = (_Float16)0.f;
        aH[tid] = z;
    }
    __syncthreads();

    const int cellbase0 = ((n_0 >> 5) << 6) + (((n_0 >> 3) & 3) << 4);
    const int cellbase1 = ((n_1 >> 5) << 6) + (((n_1 >> 3) & 3) << 4);

    int buf = 0;
    for (int s = 0; s < 128; ++s) {
        // phase 1: A-frags from LDS (lane-contiguous b128)
        half8 axr[8], ahr[8];
#pragma unroll
        for (int f = 0; f < 8; ++f) {
            axr[f] = aX[buf][(f << 6) + lane];
            ahr[f] = aH[(f << 6) + lane];
        }
        const int pf = (s + 1 < 128);
        if (d > 0 && pf) waitflag(s + 2);   // producer's step s+1 done?
        __syncthreads();

        // phase 2: prefetch next step's x-input (hidden behind MFMAs)
        half8 px;
        if (pf) px = stage(s + 1);

        // phase 3: D = Xin@Wih^T + Hprev@Whh^T + bias
        float4v acc0 = {bias0, bias0, bias0, bias0};
        float4v acc1 = {bias1, bias1, bias1, bias1};
#pragma unroll
        for (int f = 0; f < 8; ++f) {
            acc0 = __builtin_amdgcn_mfma_f32_16x16x32_f16(axr[f], Bih0[f], acc0, 0, 0, 0);
            acc1 = __builtin_amdgcn_mfma_f32_16x16x32_f16(axr[f], Bih1[f], acc1, 0, 0, 0);
            acc0 = __builtin_amdgcn_mfma_f32_16x16x32_f16(ahr[f], Bhh0[f], acc0, 0, 0, 0);
            acc1 = __builtin_amdgcn_mfma_f32_16x16x32_f16(ahr[f], Bhh1[f], acc1, 0, 0, 0);
        }

        // phase 4/5: tanh, store h to d_out (fp32, final layout), scatter to aH
        unsigned short* aHu = (unsigned short*)aH;
#pragma unroll
        for (int r = 0; r < 4; ++r) {
            const float h0 = fast_tanh(acc0[r]);
            const float h1 = fast_tanh(acc1[r]);
            const int m = (quad << 2) + r;
            const int chain = c0 + m;
            const int i = isY ? chain : s;
            const int j = isY ? s : ((chain + s) & 127);
            const size_t cell = (size_t)(b * SS + i) * TT + j;
            float* orow = out + cell * 2 * HH + (size_t)slot * HH;
            orow[n_0] = h0;
            orow[n_1] = h1;
            aHu[((cellbase0 + m) << 3) + (n_0 & 7)] = f2hbits(h0);
            aHu[((cellbase1 + m) << 3) + (n_1 & 7)] = f2hbits(h1);
        }
        if (pf) aX[buf ^ 1][tid] = px;

        if (d < 2) __threadfence();          // make h-stores agent-visible
        __syncthreads();                     // all threads' stores drained
        if (d < 2 && tid == 0)
            __hip_atomic_store(myflag, s + 1, __ATOMIC_RELEASE, __HIP_MEMORY_SCOPE_AGENT);
        buf ^= 1;
    }
    (void)wv;
}

extern "C" void kernel_launch(void* const* d_in, const int* in_sizes, int n_in,
                              void* d_out, int out_size, void* d_ws, size_t ws_size,
                              hipStream_t stream) {
    const float* src   = (const float*)d_in[0];
    const float* trg   = (const float*)d_in[1];
    const float* Wx_ih = (const float*)d_in[2];
    const float* Wx_hh = (const float*)d_in[3];
    const float* bx_ih = (const float*)d_in[4];
    const float* bx_hh = (const float*)d_in[5];
    const float* Wy_ih = (const float*)d_in[6];
    const float* Wy_hh = (const float*)d_in[7];
    const float* by_ih = (const float*)d_in[8];
    const float* by_hh = (const float*)d_in[9];
    float* out = (float*)d_out;
    int* flags = (int*)d_ws;

    // zero the 192 progress flags (ws is poisoned 0xAA before every call)
    hipMemsetAsync(flags, 0, 256 * sizeof(int), stream);

    hipLaunchKernelGGL(grid_rnn_pipe, dim3(192), dim3(512), 0, stream,
                       src, trg, Wx_ih, Wx_hh, bx_ih, bx_hh,
                       Wy_ih, Wy_hh, by_ih, by_hh, out, flags);
}

// Round 4
// 1332.877 us; speedup vs baseline: 4.3406x; 4.3406x over previous
//
#include <hip/hip_runtime.h>

// GridRNN B=4, S=T=128, H=256, D=3.
// Round-4 structure: sequential depths (3 dispatches), 64 wgs x 256 threads.
// Each wg owns 16 chains (X-diagonals or Y-rows); 4 waves, each wave computes
// an N=64 output slice (4 MFMA tiles). Weights (B-frags) VGPR-resident
// (256 VGPRs). X-input A-frags loaded per-wave straight from global
// (f16 ws grid; 16 B/lane = one frag), prefetched one step ahead; L1 dedupes
// the 4x re-read. LDS carries only the h-state (double-buffered A-frag
// layout, one barrier/step). Intermediates: f16 grids in d_ws (ws_size
// verified >= 67 MB in round 2); final depth writes fp32 d_out.

#define SS 128
#define TT 128
#define HH 256
#define GRID_ELEMS ((size_t)4 * 128 * 128 * 256)

typedef _Float16 half8 __attribute__((ext_vector_type(8)));
typedef float float4v __attribute__((ext_vector_type(4)));

__device__ __forceinline__ float fast_tanh(float x) {
    float e = __expf(2.0f * x);
    return 1.0f - 2.0f / (e + 1.0f);
}

__device__ __forceinline__ unsigned short f2hbits(float x) {
    _Float16 h = (_Float16)x;
    return __builtin_bit_cast(unsigned short, h);
}

extern "C" __global__ void __launch_bounds__(256, 1)
grid_rnn_w4(const float* __restrict__ src, const float* __restrict__ trg,
            const float* __restrict__ Wx_ih, const float* __restrict__ Wx_hh,
            const float* __restrict__ bx_ih, const float* __restrict__ bx_hh,
            const float* __restrict__ Wy_ih, const float* __restrict__ Wy_hh,
            const float* __restrict__ by_ih, const float* __restrict__ by_hh,
            float* __restrict__ out, unsigned short* __restrict__ ws,
            int d, int use_ws)
{
    __shared__ half8 aH[2][512];   // h-state A-frags, double buffered (8 KB x2)

    const int tid  = threadIdx.x;
    const int lane = tid & 63;
    const int wv   = tid >> 6;     // wave 0..3 -> N-slice base wv*64
    const int q    = lane >> 4;    // k-quad within A/B frags
    const int l15  = lane & 15;    // A row (chain-in-group) / B col (within tile)

    const int bid  = blockIdx.x;   // 0..63
    const int isY  = bid >= 32;
    const int g    = isY ? bid - 32 : bid;
    const int b    = g >> 3;       // batch
    const int c0   = (g & 7) << 4; // first chain of the 16-chain group
    const int slot = isY;

    const float* Wih = (isY ? Wy_ih : Wx_ih) + (size_t)d * HH * HH;
    const float* Whh = (isY ? Wy_hh : Wx_hh) + (size_t)d * HH * HH;
    const float* bih = (isY ? by_ih : bx_ih) + d * HH;
    const float* bhh = (isY ? by_hh : bx_hh) + d * HH;
    unsigned short* wsg = ws + (size_t)isY * GRID_ELEMS;

    // ---- B fragments (weights) in VGPRs: 4 tiles x 8 k-frags x 2 mats = 256 VGPRs.
    // B[k = f*32 + q*8 + j][n = tile_base + l15] = W[n][k].
    half8 Bih[4][8], Bhh[4][8];
    float bias[4];
    {
        auto ldfrag = [&](const float* rowp, int k) -> half8 {
            const float4v u0 = *(const float4v*)(rowp + k);
            const float4v u1 = *(const float4v*)(rowp + k + 4);
            half8 v;
#pragma unroll
            for (int e = 0; e < 4; ++e) { v[e] = (_Float16)u0[e]; v[4 + e] = (_Float16)u1[e]; }
            return v;
        };
#pragma unroll
        for (int t = 0; t < 4; ++t) {
            const int n = (wv << 6) + (t << 4) + l15;
            const float* ri = Wih + (size_t)n * HH;
            const float* rh = Whh + (size_t)n * HH;
#pragma unroll
            for (int f = 0; f < 8; ++f) {
                const int k = (f << 5) + (q << 3);
                Bih[t][f] = ldfrag(ri, k);
                Bhh[t][f] = ldfrag(rh, k);
            }
            bias[t] = bih[n] + bhh[n];
        }
    }

    // ---- X A-frag loader: lane owns row m=l15 (chain c0+l15), k0 = f*32+q*8.
    const int mychain = c0 + l15;
    const int k0base  = q << 3;

    auto load_x = [&](int sn, half8* dst) {
        const int i = isY ? mychain : sn;
        const int j = isY ? sn : ((mychain + sn) & 127);
        const size_t cell = (size_t)(b * SS + i) * TT + j;
        if (d == 0) {
            const float* row = isY ? (trg + (size_t)(b * TT + j) * HH)
                                   : (src + (size_t)(b * SS + i) * HH);
#pragma unroll
            for (int f = 0; f < 8; ++f) {
                const int k = (f << 5) + k0base;
                const float4v u0 = *(const float4v*)(row + k);
                const float4v u1 = *(const float4v*)(row + k + 4);
                half8 v;
#pragma unroll
                for (int e = 0; e < 4; ++e) { v[e] = (_Float16)u0[e]; v[4 + e] = (_Float16)u1[e]; }
                dst[f] = v;
            }
        } else if (use_ws) {
            const unsigned short* row = wsg + cell * HH;
#pragma unroll
            for (int f = 0; f < 8; ++f)
                dst[f] = *(const half8*)(row + (f << 5) + k0base);
        } else {
            const float* row = out + cell * 2 * HH + (size_t)slot * HH;
#pragma unroll
            for (int f = 0; f < 8; ++f) {
                const int k = (f << 5) + k0base;
                const float4v u0 = *(const float4v*)(row + k);
                const float4v u1 = *(const float4v*)(row + k + 4);
                half8 v;
#pragma unroll
                for (int e = 0; e < 4; ++e) { v[e] = (_Float16)u0[e]; v[4 + e] = (_Float16)u1[e]; }
                dst[f] = v;
            }
        }
    };

    // ---- init: zero h-state buf 0, preload X(0).
    {
        half8 z;
#pragma unroll
        for (int e = 0; e < 8; ++e) z[e] = (_Float16)0.f;
        aH[0][tid] = z;
        aH[0][tid + 256] = z;
    }
    half8 xf[8];
    load_x(0, xf);
    __syncthreads();

    int buf = 0;
    for (int s = 0; s < 128; ++s) {
        // prefetch next step's X (consumed next iteration; vmcnt covers MFMAs)
        half8 xn[8];
        const int pf = (s + 1 < 128);
        if (pf) load_x(s + 1, xn);

        // h-state A-frags from LDS (lane-contiguous b128)
        half8 ahr[8];
#pragma unroll
        for (int f = 0; f < 8; ++f)
            ahr[f] = aH[buf][(f << 6) + lane];

        // D = Xin@Wih^T + Hprev@Whh^T + bias : 64 MFMAs, 4 acc chains.
        // X-term first (registers ready); H-term second (LDS lands meanwhile).
        float4v acc[4];
#pragma unroll
        for (int t = 0; t < 4; ++t) acc[t] = float4v{bias[t], bias[t], bias[t], bias[t]};
#pragma unroll
        for (int f = 0; f < 8; ++f) {
#pragma unroll
            for (int t = 0; t < 4; ++t)
                acc[t] = __builtin_amdgcn_mfma_f32_16x16x32_f16(xf[f], Bih[t][f], acc[t], 0, 0, 0);
        }
#pragma unroll
        for (int f = 0; f < 8; ++f) {
#pragma unroll
            for (int t = 0; t < 4; ++t)
                acc[t] = __builtin_amdgcn_mfma_f32_16x16x32_f16(ahr[f], Bhh[t][f], acc[t], 0, 0, 0);
        }

        // epilogue: tanh, global store, scatter into aH[buf^1] in A-frag order
        unsigned short* aHu = (unsigned short*)aH[buf ^ 1];
#pragma unroll
        for (int t = 0; t < 4; ++t) {
            const int n = (wv << 6) + (t << 4) + l15;
#pragma unroll
            for (int r = 0; r < 4; ++r) {
                const float h = fast_tanh(acc[t][r]);
                const int m = (q << 2) + r;          // C/D row = chain-in-group
                const int chain = c0 + m;
                const int i = isY ? chain : s;
                const int j = isY ? s : ((chain + s) & 127);
                const size_t cell = (size_t)(b * SS + i) * TT + j;
                if (d == 2 || !use_ws)
                    out[cell * 2 * HH + (size_t)slot * HH + n] = h;
                if (d < 2 && use_ws)
                    wsg[cell * HH + n] = f2hbits(h);
                aHu[((((n >> 3) << 4) + m) << 3) + (n & 7)] = f2hbits(h);
            }
        }
        __syncthreads();
#pragma unroll
        for (int f = 0; f < 8; ++f) xf[f] = xn[f];
        buf ^= 1;
    }
}

extern "C" void kernel_launch(void* const* d_in, const int* in_sizes, int n_in,
                              void* d_out, int out_size, void* d_ws, size_t ws_size,
                              hipStream_t stream) {
    const float* src   = (const float*)d_in[0];
    const float* trg   = (const float*)d_in[1];
    const float* Wx_ih = (const float*)d_in[2];
    const float* Wx_hh = (const float*)d_in[3];
    const float* bx_ih = (const float*)d_in[4];
    const float* bx_hh = (const float*)d_in[5];
    const float* Wy_ih = (const float*)d_in[6];
    const float* Wy_hh = (const float*)d_in[7];
    const float* by_ih = (const float*)d_in[8];
    const float* by_hh = (const float*)d_in[9];
    float* out = (float*)d_out;
    unsigned short* ws = (unsigned short*)d_ws;

    const size_t need = 2 * GRID_ELEMS * sizeof(unsigned short);  // 67.1 MB
    const int use_ws = (ws_size >= need) ? 1 : 0;

    for (int d = 0; d < 3; ++d) {
        hipLaunchKernelGGL(grid_rnn_w4, dim3(64), dim3(256), 0, stream,
                           src, trg, Wx_ih, Wx_hh, bx_ih, bx_hh,
                           Wy_ih, Wy_hh, by_ih, by_hh, out, ws, d, use_ws);
    }
}

// Round 5
// 783.556 us; speedup vs baseline: 7.3837x; 1.7011x over previous
//
#include <hip/hip_runtime.h>

// GridRNN B=4, S=T=128, H=256, D=3 — MFMA, single-barrier, coalesced stores.
// 64 wgs x 512 thr (8 waves, N=32/wave); 16 chains/wg (X-diagonals / Y-rows).
// Per step: [16x256]@[256x256]^T x2 via mfma_f32_16x16x32_f16.
// LDS A-frag layout: entry e = f*64 + q*16 + m  <=>  A[m][k=f*32+q*8..+7],
// which is ALSO n-major chunks: entry tid <=> (m=tid&15, n0=(tid>>4)*8).
// Both aX and aH double-buffered -> ONE __syncthreads per step.
// Global h-store: LDS readback (entry tid) -> one 16B store/thread/step.

#define SS 128
#define TT 128
#define HH 256
#define GRID_ELEMS ((size_t)4 * 128 * 128 * 256)

typedef _Float16 half8 __attribute__((ext_vector_type(8)));
typedef float float4v __attribute__((ext_vector_type(4)));

__device__ __forceinline__ float fast_tanh(float x) {
    float e = __expf(2.0f * x);
    return 1.0f - 2.0f / (e + 1.0f);
}

__device__ __forceinline__ unsigned short f2hbits(float x) {
    _Float16 h = (_Float16)x;
    return __builtin_bit_cast(unsigned short, h);
}

extern "C" __global__ void __launch_bounds__(512, 2)
grid_rnn_r5(const float* __restrict__ src, const float* __restrict__ trg,
            const float* __restrict__ Wx_ih, const float* __restrict__ Wx_hh,
            const float* __restrict__ bx_ih, const float* __restrict__ bx_hh,
            const float* __restrict__ Wy_ih, const float* __restrict__ Wy_hh,
            const float* __restrict__ by_ih, const float* __restrict__ by_hh,
            float* __restrict__ out, unsigned short* __restrict__ ws,
            int d, int use_ws)
{
    __shared__ half8 aX[2][512];   // x-input A-frags, double buffered (8 KB x2)
    __shared__ half8 aH[2][512];   // h-state A-frags, double buffered (8 KB x2)

    const int tid  = threadIdx.x;
    const int lane = tid & 63;
    const int wv   = tid >> 6;     // wave 0..7 -> N-slice n0 = 32*wv
    const int quad = lane >> 4;
    const int l15  = lane & 15;

    const int bid  = blockIdx.x;   // 0..63
    const int isY  = bid >= 32;
    const int g    = isY ? bid - 32 : bid;
    const int b    = g >> 3;       // batch
    const int c0   = (g & 7) << 4; // first chain of the 16-chain group
    const int slot = isY;

    const float* Wih = (isY ? Wy_ih : Wx_ih) + (size_t)d * HH * HH;
    const float* Whh = (isY ? Wy_hh : Wx_hh) + (size_t)d * HH * HH;
    const float* bih = (isY ? by_ih : bx_ih) + d * HH;
    const float* bhh = (isY ? by_hh : bx_hh) + d * HH;
    unsigned short* wsg = ws + (size_t)isY * GRID_ELEMS;

    const int n_0 = (wv << 5) + l15;   // tile-0 column
    const int n_1 = n_0 + 16;          // tile-1 column

    // ---- B fragments (weights), register-resident.
    half8 Bih0[8], Bih1[8], Bhh0[8], Bhh1[8];
    {
        auto ldfrag = [&](const float* rowp, int k) -> half8 {
            const float4v u0 = *(const float4v*)(rowp + k);
            const float4v u1 = *(const float4v*)(rowp + k + 4);
            half8 v;
#pragma unroll
            for (int e = 0; e < 4; ++e) { v[e] = (_Float16)u0[e]; v[4 + e] = (_Float16)u1[e]; }
            return v;
        };
        const float* r0i = Wih + (size_t)n_0 * HH;
        const float* r1i = Wih + (size_t)n_1 * HH;
        const float* r0h = Whh + (size_t)n_0 * HH;
        const float* r1h = Whh + (size_t)n_1 * HH;
#pragma unroll
        for (int f = 0; f < 8; ++f) {
            const int k = (f << 5) + (quad << 3);
            Bih0[f] = ldfrag(r0i, k);
            Bih1[f] = ldfrag(r1i, k);
            Bhh0[f] = ldfrag(r0h, k);
            Bhh1[f] = ldfrag(r1h, k);
        }
    }
    const float bias0 = bih[n_0] + bhh[n_0];
    const float bias1 = bih[n_1] + bhh[n_1];

    // ---- staging: thread tid owns A-frag entry tid: m=tid&15, k0=(tid>>4)*8.
    const int cm  = tid & 15;
    const int ck0 = (tid >> 4) << 3;
    const int chc = c0 + cm;

    auto stage = [&](int sn) -> half8 {
        const int i = isY ? chc : sn;
        const int j = isY ? sn : ((chc + sn) & 127);
        const size_t cell = (size_t)(b * SS + i) * TT + j;
        half8 v;
        if (d == 0) {
            const float* row = isY ? (trg + (size_t)(b * TT + j) * HH)
                                   : (src + (size_t)(b * SS + i) * HH);
            const float4v u0 = *(const float4v*)(row + ck0);
            const float4v u1 = *(const float4v*)(row + ck0 + 4);
#pragma unroll
            for (int e = 0; e < 4; ++e) { v[e] = (_Float16)u0[e]; v[4 + e] = (_Float16)u1[e]; }
        } else if (use_ws) {
            v = *(const half8*)(wsg + cell * HH + ck0);
        } else {
            const float* row = out + cell * 2 * HH + (size_t)slot * HH + ck0;
            const float4v u0 = *(const float4v*)(row);
            const float4v u1 = *(const float4v*)(row + 4);
#pragma unroll
            for (int e = 0; e < 4; ++e) { v[e] = (_Float16)u0[e]; v[4 + e] = (_Float16)u1[e]; }
        }
        return v;
    };

    // ---- coalesced h-store: thread tid stores chunk (cell m=tid&15, n0=(tid>>4)*8)
    auto store_h = [&](int sp, int bufi) {
        const half8 v = aH[bufi][tid];
        const int i = isY ? chc : sp;
        const int j = isY ? sp : ((chc + sp) & 127);
        const size_t cell = (size_t)(b * SS + i) * TT + j;
        if (d == 2 || !use_ws) {
            float* p = out + cell * 2 * HH + (size_t)slot * HH + ck0;
            float4v u0, u1;
#pragma unroll
            for (int e = 0; e < 4; ++e) { u0[e] = (float)v[e]; u1[e] = (float)v[4 + e]; }
            *(float4v*)p = u0;
            *(float4v*)(p + 4) = u1;
        }
        if (d < 2 && use_ws) {
            *(half8*)(wsg + cell * HH + ck0) = v;
        }
    };

    // ---- init: zero h-state buf 0, stage X(0) into aX[0].
    {
        half8 z;
#pragma unroll
        for (int e = 0; e < 8; ++e) z[e] = (_Float16)0.f;
        aH[0][tid] = z;
    }
    aX[0][tid] = stage(0);
    __syncthreads();

    const int cellbase0 = ((n_0 >> 5) << 6) + (((n_0 >> 3) & 3) << 4);
    const int cellbase1 = ((n_1 >> 5) << 6) + (((n_1 >> 3) & 3) << 4);

    int buf = 0;
    for (int s = 0; s < 128; ++s) {
        // phase A: coalesced global store of h(s-1) (retires during MFMA phase)
        if (s > 0) store_h(s - 1, buf);

        // phase B: A-frags from LDS (lane-contiguous b128, broadcast)
        half8 axr[8], ahr[8];
#pragma unroll
        for (int f = 0; f < 8; ++f) {
            axr[f] = aX[buf][(f << 6) + lane];
            ahr[f] = aH[buf][(f << 6) + lane];
        }

        // phase C: prefetch next step's x-input (global -> reg)
        const int pf = (s + 1 < 128);
        half8 px;
        if (pf) px = stage(s + 1);

        // phase D: D = Xin@Wih^T + Hprev@Whh^T + bias (split acc: 8-deep chains)
        float4v ax0 = {bias0, bias0, bias0, bias0};
        float4v ax1 = {bias1, bias1, bias1, bias1};
        float4v ah0 = {0.f, 0.f, 0.f, 0.f};
        float4v ah1 = {0.f, 0.f, 0.f, 0.f};
#pragma unroll
        for (int f = 0; f < 8; ++f) {
            ax0 = __builtin_amdgcn_mfma_f32_16x16x32_f16(axr[f], Bih0[f], ax0, 0, 0, 0);
            ax1 = __builtin_amdgcn_mfma_f32_16x16x32_f16(axr[f], Bih1[f], ax1, 0, 0, 0);
            ah0 = __builtin_amdgcn_mfma_f32_16x16x32_f16(ahr[f], Bhh0[f], ah0, 0, 0, 0);
            ah1 = __builtin_amdgcn_mfma_f32_16x16x32_f16(ahr[f], Bhh1[f], ah1, 0, 0, 0);
        }

        // phase E: tanh + scatter h(s) into aH[buf^1]; stage X(s+1) into aX[buf^1]
        unsigned short* aHu = (unsigned short*)aH[buf ^ 1];
#pragma unroll
        for (int r = 0; r < 4; ++r) {
            const float h0 = fast_tanh(ax0[r] + ah0[r]);
            const float h1 = fast_tanh(ax1[r] + ah1[r]);
            const int m = (quad << 2) + r;
            aHu[((cellbase0 + m) << 3) + (n_0 & 7)] = f2hbits(h0);
            aHu[((cellbase1 + m) << 3) + (n_1 & 7)] = f2hbits(h1);
        }
        if (pf) aX[buf ^ 1][tid] = px;

        __syncthreads();   // the ONLY barrier per step
        buf ^= 1;
    }

    // epilogue: store h(127)
    store_h(127, buf);
}

extern "C" void kernel_launch(void* const* d_in, const int* in_sizes, int n_in,
                              void* d_out, int out_size, void* d_ws, size_t ws_size,
                              hipStream_t stream) {
    const float* src   = (const float*)d_in[0];
    const float* trg   = (const float*)d_in[1];
    const float* Wx_ih = (const float*)d_in[2];
    const float* Wx_hh = (const float*)d_in[3];
    const float* bx_ih = (const float*)d_in[4];
    const float* bx_hh = (const float*)d_in[5];
    const float* Wy_ih = (const float*)d_in[6];
    const float* Wy_hh = (const float*)d_in[7];
    const float* by_ih = (const float*)d_in[8];
    const float* by_hh = (const float*)d_in[9];
    float* out = (float*)d_out;
    unsigned short* ws = (unsigned short*)d_ws;

    const size_t need = 2 * GRID_ELEMS * sizeof(unsigned short);  // 67.1 MB
    const int use_ws = (ws_size >= need) ? 1 : 0;

    for (int d = 0; d < 3; ++d) {
        hipLaunchKernelGGL(grid_rnn_r5, dim3(64), dim3(512), 0, stream,
                           src, trg, Wx_ih, Wx_hh, bx_ih, bx_hh,
                           Wy_ih, Wy_hh, by_ih, by_hh, out, ws, d, use_ws);
    }
}